// Round 17
// baseline (308.928 us; speedup 1.0000x reference)
//
#include <hip/hip_runtime.h>
#include <hip/hip_bf16.h>
#include <cstdint>
#include <cstddef>

#define DEVI __device__ __forceinline__

typedef unsigned short u16;
using frag_ab = __attribute__((ext_vector_type(8))) short;   // 8 bf16 (4 VGPRs)
using f32x4   = __attribute__((ext_vector_type(4))) float;   // mfma acc / 16B NT store

constexpr int HW = 16384;   // 128*128 spatial
constexpr int NC = 256;     // channels (Cin = Cout = 256)

DEVI u16 bf16bits(float f) {
    union { float f; uint32_t u; } cv; cv.f = f;
    uint32_t u = cv.u;
    u += 0x7fffu + ((u >> 16) & 1u);   // RNE
    return (u16)(u >> 16);
}

DEVI void gload16(const void* g, void* l) {
    __builtin_amdgcn_global_load_lds(
        (const __attribute__((address_space(1))) uint32_t*)g,
        (__attribute__((address_space(3))) uint32_t*)l, 16, 0, 0);
}

// LDS slab: [row][64B]; 16B slot s at phys slot s ^ (row&3) ^ ((row>>2)&3).
DEVI frag_ab read_frag(const u16* slab, int row, int l4) {
    const int phys = (l4 ^ row ^ (row >> 2)) & 3;
    return *(const frag_ab*)((const char*)slab + row * 64 + phys * 16);
}

// ---------------- pass 1: x partial stats + transpose to xt[b][p][c] bf16 ----------------
__global__ __launch_bounds__(256) void transpose_stats_kernel(
    const float* __restrict__ x, u16* __restrict__ xt,
    float* __restrict__ ps, float* __restrict__ pq)
{
    constexpr int PADW = 68;                       // row pitch in u16 (136B)
    __shared__ __align__(16) u16 tile[64 * PADW];  // [px][ch]
    const int b = blockIdx.z, c0 = blockIdx.y * 64, p0 = blockIdx.x * 64;
    const int pblk = blockIdx.x;                   // 0..255
    const int t = threadIdx.x;
    const int lane = t & 63, w = t >> 6;
    const int pq_ = lane & 15, cq = lane >> 4;
    const int quad = w * 4 + cq;                   // ch-quad 0..15
    const float* xb = x + ((size_t)b * NC + c0) * HW + p0;

    float va[4][4];                                // [j=ch][i=px]
    float aS[4], aQ[4];
    #pragma unroll
    for (int j = 0; j < 4; ++j) {
        const float4 v = *(const float4*)(xb + (size_t)(quad * 4 + j) * HW + pq_ * 4);
        va[j][0] = v.x; va[j][1] = v.y; va[j][2] = v.z; va[j][3] = v.w;
        float s1 = v.x + v.y + v.z + v.w;
        float s2 = v.x*v.x + v.y*v.y + v.z*v.z + v.w*v.w;
        #pragma unroll
        for (int d = 1; d < 16; d <<= 1) {
            s1 += __shfl_xor(s1, d, 64);
            s2 += __shfl_xor(s2, d, 64);
        }
        aS[j] = s1; aQ[j] = s2;
    }
    if (pq_ == 0) {
        const float4 vs = {aS[0], aS[1], aS[2], aS[3]};
        const float4 vq = {aQ[0], aQ[1], aQ[2], aQ[3]};
        *(float4*)&ps[((size_t)b * 256 + pblk) * NC + c0 + quad * 4] = vs;
        *(float4*)&pq[((size_t)b * 256 + pblk) * NC + c0 + quad * 4] = vq;
    }
    #pragma unroll
    for (int i = 0; i < 4; ++i) {
        alignas(8) u16 pk[4];
        #pragma unroll
        for (int j = 0; j < 4; ++j) pk[j] = bf16bits(va[j][i]);
        *(uint2*)&tile[(pq_ * 4 + i) * PADW + quad * 4] = *(const uint2*)pk;
    }
    __syncthreads();
    const int pl = t >> 2, q = t & 3;
    u16* dst = xt + ((size_t)b * HW + p0 + pl) * NC + c0;
    #pragma unroll
    for (int s = 0; s < 2; ++s) {
        const int ch8 = q + s * 4;
        const uint2 lo = *(const uint2*)&tile[pl * PADW + ch8 * 8];
        const uint2 hi = *(const uint2*)&tile[pl * PADW + ch8 * 8 + 4];
        const uint4 o4 = {lo.x, lo.y, hi.x, hi.y};
        *(uint4*)(dst + ch8 * 8) = o4;
    }
}

// ---------------- fold (512 threads): reduce partials -> mu/rs, fold IN into weights/bias ----------------
__global__ __launch_bounds__(512) void fold_kernel(
    const float* __restrict__ w, const float* __restrict__ bias,
    const float* __restrict__ ps, const float* __restrict__ pq,
    u16* __restrict__ we, float* __restrict__ be)
{
    const int b = blockIdx.y, oc = blockIdx.x * 64;
    __shared__ float mu[NC], rs[NC];
    __shared__ float m1[2][NC], m2[2][NC];
    __shared__ __align__(16) float wt[64 * NC];
    const int t = threadIdx.x;
    {
        const int c = t & 255, half = t >> 8;      // half 0: i 0..127, half 1: i 128..255
        float s1 = 0.f, s2 = 0.f;
        const float* pp = ps + (size_t)b * 256 * NC + (size_t)half * 128 * NC + c;
        const float* qq = pq + (size_t)b * 256 * NC + (size_t)half * 128 * NC + c;
        for (int i = 0; i < 128; ++i) {
            s1 += pp[(size_t)i * NC];
            s2 += qq[(size_t)i * NC];
        }
        m1[half][c] = s1; m2[half][c] = s2;
    }
    #pragma unroll
    for (int i = 0; i < 8; ++i)
        *(float4*)&wt[i*2048 + t*4] = *(const float4*)&w[(size_t)oc*NC + i*2048 + t*4];
    __syncthreads();
    if (t < NC) {
        const float s1 = m1[0][t] + m1[1][t];
        const float s2 = m2[0][t] + m2[1][t];
        const float m = s1 * (1.0f / HW);
        mu[t] = m;
        rs[t] = rsqrtf(s2 * (1.0f / HW) - m * m + 1e-5f);
    }
    __syncthreads();
    const int o = oc + (t >> 3), q = t & 7;        // 8 threads per o-row, 32 ch each
    const float* wrow = &wt[(t >> 3) * NC];
    u16* werow = we + ((size_t)b * NC + o) * NC;
    float bacc = 0.f;
    for (int cc = 0; cc < 4; ++cc) {
        alignas(16) u16 pk[8];
        #pragma unroll
        for (int jj = 0; jj < 8; ++jj) {
            const int c = q*32 + cc*8 + jj;
            const float wv = wrow[c];
            bacc -= wv * mu[c] * rs[c];
            pk[jj] = bf16bits(wv * rs[c]);
        }
        *(uint4*)(werow + q*32 + cc*8) = *(const uint4*)pk;
    }
    bacc += __shfl_xor(bacc, 1, 64);
    bacc += __shfl_xor(bacc, 2, 64);
    bacc += __shfl_xor(bacc, 4, 64);
    if (q == 0) be[b*NC + o] = bias[o] + bacc;
}

// ---------------- GEMM1: 8-wave high-occupancy variant (same traffic as r16) ----------------
// Block 512 thr = 8 waves; block covers 64 px x 256 outs (pixels read ONCE).
// Wave wid owns outs [wid*32, +32): wf[8][2] = 64 VGPR; (512,4) caps VGPR at 128
// -> 2 blocks/CU = 16 waves/CU (2x r16). Counted vmcnt valid for ALL lanes:
// per tile all-lane stores = 8 (ht uint2), loads = 4 -> vmcnt(8) retires the loads.
__global__ __launch_bounds__(512, 4) void gemm1_kernel(
    const u16* __restrict__ pixM,   // xt [B*HW][NC]
    const u16* __restrict__ wMat,   // w1e [B][NC][NC]
    const float* __restrict__ biasE,// b1e [B][NC]
    u16* __restrict__ outB,         // ht
    float* __restrict__ hps, float* __restrict__ hpq)
{
    __shared__ __align__(16) u16 ldsP[2][16384];  // 2 strips: 64 px x 256 k (32 KB each)

    const int b = blockIdx.x >> 6;
    const int g = blockIdx.x & 63;                // tiles pblk = g + 64*i
    const int tid = threadIdx.x;
    const int lane = tid & 63, wid = tid >> 6;    // 8 waves
    const int l15 = lane & 15, l4 = lane >> 4, rin = lane >> 2;

    const u16* gW = wMat + (size_t)b * NC * NC;
    const int obase = wid * 32;

    auto stageP = [&](int i, int buf) {
        const u16* gPt = pixM + ((size_t)b * HW + (g + 64 * i) * 64) * NC;
        #pragma unroll
        for (int q = 0; q < 4; ++q) {
            const int j = q * 8 + wid, slice = j >> 2, rgrp = j & 3;
            const int row = rgrp * 16 + rin;
            const int sl = ((lane & 3) ^ row ^ (row >> 2)) & 3;
            gload16(gPt + (size_t)row * NC + slice * 32 + sl * 8,
                    (char*)ldsP[buf] + slice * 4096 + rgrp * 1024);
        }
    };

    frag_ab wf[8][2];
    {
        const u16* wb = gW + (size_t)(obase + l15) * NC + l4 * 8;
        #pragma unroll
        for (int ks = 0; ks < 8; ++ks)
            #pragma unroll
            for (int f = 0; f < 2; ++f)
                wf[ks][f] = *(const frag_ab*)(wb + (size_t)f * 16 * NC + ks * 32);
    }
    float4 vb[2];
    #pragma unroll
    for (int mi = 0; mi < 2; ++mi)
        vb[mi] = *(const float4*)&biasE[b*NC + obase + 16*mi + l4*4];

    stageP(0, 0);
    for (int i = 0; i < 4; ++i) {
        if (i == 0) asm volatile("s_waitcnt vmcnt(0)" ::: "memory");
        else        asm volatile("s_waitcnt vmcnt(8)" ::: "memory");
        __builtin_amdgcn_s_barrier();              // strip i resident for all waves
        if (i < 3) stageP(i + 1, (i + 1) & 1);
        asm volatile("" ::: "memory");             // pin stage issue vs epilogue stores

        f32x4 acc[2][4];
        #pragma unroll
        for (int mi = 0; mi < 2; ++mi)
            #pragma unroll
            for (int nj = 0; nj < 4; ++nj)
                acc[mi][nj] = (f32x4){0.f, 0.f, 0.f, 0.f};

        const u16* bufb = ldsP[i & 1];
        #pragma unroll
        for (int ks = 0; ks < 8; ++ks) {
            const u16* pslab = bufb + ks * 2048;   // 4 KB k-slice (64 rows x 64B)
            #pragma unroll
            for (int h = 0; h < 2; ++h) {          // pf 2-at-a-time: keeps VGPR under cap
                frag_ab pf[2];
                #pragma unroll
                for (int f = 0; f < 2; ++f)
                    pf[f] = read_frag(pslab, 32*h + 16*f + l15, l4);
                #pragma unroll
                for (int f2 = 0; f2 < 2; ++f2)
                    #pragma unroll
                    for (int mi = 0; mi < 2; ++mi)
                        acc[mi][2*h + f2] = __builtin_amdgcn_mfma_f32_16x16x32_bf16(
                            wf[ks][mi], pf[f2], acc[mi][2*h + f2], 0, 0, 0);
            }
        }

        const int pblk = g + 64 * i;
        const int p0 = pblk * 64;
        // acc: reg dim = out (obase+16mi+l4*4+r), lane dim = px (16nj+l15)
        u16* htbase = outB + ((size_t)b * HW + p0) * NC + obase;
        #pragma unroll
        for (int mi = 0; mi < 2; ++mi) {
            const float bx[4] = {vb[mi].x, vb[mi].y, vb[mi].z, vb[mi].w};
            float s1r[4] = {0.f,0.f,0.f,0.f}, s2r[4] = {0.f,0.f,0.f,0.f};
            #pragma unroll
            for (int nj = 0; nj < 4; ++nj) {
                u16* rowp = htbase + (size_t)(16*nj + l15) * NC;
                alignas(8) u16 pk[4];
                #pragma unroll
                for (int r = 0; r < 4; ++r) {
                    const float v = fmaxf(acc[mi][nj][r] + bx[r], 0.f);
                    s1r[r] += v; s2r[r] += v * v;
                    pk[r] = bf16bits(v);
                }
                *(uint2*)&rowp[16*mi + l4*4] = *(const uint2*)pk;   // 8B store (all lanes)
            }
            #pragma unroll
            for (int r = 0; r < 4; ++r) {
                float a1 = s1r[r], a2 = s2r[r];
                #pragma unroll
                for (int d = 1; d < 16; d <<= 1) {
                    a1 += __shfl_xor(a1, d, 64);
                    a2 += __shfl_xor(a2, d, 64);
                }
                s1r[r] = a1; s2r[r] = a2;
            }
            if (l15 == 0) {
                const int o = obase + 16*mi + l4*4;
                const float4 w1v = {s1r[0], s1r[1], s1r[2], s1r[3]};
                const float4 w2v = {s2r[0], s2r[1], s2r[2], s2r[3]};
                *(float4*)&hps[((size_t)b * 256 + pblk) * NC + o] = w1v;
                *(float4*)&hpq[((size_t)b * 256 + pblk) * NC + o] = w2v;
            }
        }
    }
}

// ---------------- GEMM2: r16-proven 4-wave variant, NT out stores ----------------
// vmcnt(16) uniform-correct: all lanes issue 16 out stores + 8 loads per tile.
__global__ __launch_bounds__(256, 2) void gemm2_kernel(
    const u16* __restrict__ pixM,   // ht [B*HW][NC]
    const u16* __restrict__ wMat,   // w2e [B][NC][NC]
    const float* __restrict__ biasE,// b2e [B][NC]
    float* __restrict__ outF)       // out [B][NC][HW]
{
    __shared__ __align__(16) u16 ldsP[2][16384];

    const int b = blockIdx.x >> 6;
    const int g = blockIdx.x & 63;
    const int tid = threadIdx.x;
    const int lane = tid & 63, wid = tid >> 6;    // 4 waves; wave owns outs [wid*64, +64)
    const int l15 = lane & 15, l4 = lane >> 4, rin = lane >> 2;

    const u16* gW = wMat + (size_t)b * NC * NC;
    const int prow = wid * 16 + rin;
    const int psl  = ((lane & 3) ^ prow ^ (prow >> 2)) & 3;

    auto stageP = [&](int i, int buf) {
        const u16* gPt = pixM + ((size_t)b * HW + (g + 64 * i) * 64) * NC;
        #pragma unroll
        for (int ks = 0; ks < 8; ++ks)
            gload16(gPt + (size_t)prow * NC + ks * 32 + psl * 8,
                    (char*)ldsP[buf] + ks * 4096 + wid * 1024);
    };

    frag_ab wf[8][4];
    {
        const u16* wb = gW + (size_t)(wid * 64 + l15) * NC + l4 * 8;
        #pragma unroll
        for (int ks = 0; ks < 8; ++ks)
            #pragma unroll
            for (int f = 0; f < 4; ++f)
                wf[ks][f] = *(const frag_ab*)(wb + (size_t)f * 16 * NC + ks * 32);
    }
    float bm[4];
    #pragma unroll
    for (int ni = 0; ni < 4; ++ni)
        bm[ni] = biasE[b*NC + wid*64 + 16*ni + l15];

    stageP(0, 0);
    for (int i = 0; i < 4; ++i) {
        if (i == 0) asm volatile("s_waitcnt vmcnt(0)" ::: "memory");
        else        asm volatile("s_waitcnt vmcnt(16)" ::: "memory");
        __builtin_amdgcn_s_barrier();
        if (i < 3) stageP(i + 1, (i + 1) & 1);
        asm volatile("" ::: "memory");

        f32x4 acc[4][4];
        #pragma unroll
        for (int mi = 0; mi < 4; ++mi)
            #pragma unroll
            for (int ni = 0; ni < 4; ++ni)
                acc[mi][ni] = (f32x4){0.f, 0.f, 0.f, 0.f};

        const u16* bufb = ldsP[i & 1];
        #pragma unroll
        for (int ks = 0; ks < 8; ++ks) {
            const u16* pslab = bufb + ks * 2048;
            frag_ab pf[4];
            #pragma unroll
            for (int f = 0; f < 4; ++f)
                pf[f] = read_frag(pslab, 16 * f + l15, l4);
            #pragma unroll
            for (int ni = 0; ni < 4; ++ni)
                #pragma unroll
                for (int mi = 0; mi < 4; ++mi)
                    acc[mi][ni] = __builtin_amdgcn_mfma_f32_16x16x32_bf16(
                        pf[mi], wf[ks][ni], acc[mi][ni], 0, 0, 0);
        }

        const int p0 = (g + 64 * i) * 64;
        // acc: reg dim = px (16mi+l4*4+r), lane dim = out (wid*64+16ni+l15)
        #pragma unroll
        for (int ni = 0; ni < 4; ++ni) {
            const int o = wid*64 + 16*ni + l15;
            float* colp = outF + ((size_t)b * NC + o) * HW + p0;
            #pragma unroll
            for (int mi = 0; mi < 4; ++mi) {
                const f32x4 v = {fmaxf(acc[mi][ni][0] + bm[ni], 0.f),
                                 fmaxf(acc[mi][ni][1] + bm[ni], 0.f),
                                 fmaxf(acc[mi][ni][2] + bm[ni], 0.f),
                                 fmaxf(acc[mi][ni][3] + bm[ni], 0.f)};
                __builtin_nontemporal_store(v, (f32x4*)&colp[16*mi + l4*4]);  // 16B NT store
            }
        }
    }
}

extern "C" void kernel_launch(void* const* d_in, const int* in_sizes, int n_in,
                              void* d_out, int out_size, void* d_ws, size_t ws_size,
                              hipStream_t stream)
{
    (void)in_sizes; (void)n_in; (void)out_size;
    const float* x  = (const float*)d_in[0];
    const float* w1 = (const float*)d_in[1];
    const float* b1 = (const float*)d_in[2];
    const float* w2 = (const float*)d_in[3];
    const float* b2 = (const float*)d_in[4];
    float* out = (float*)d_out;

    // scratch carved out of d_out (268 MB): dead before gemm2 overwrites it
    char* od = (char*)d_out;
    u16*   xt  = (u16*)od;                        // 134,217,728 B
    float* xps = (float*)(od + 134217728);        //   4,194,304
    float* xpq = (float*)(od + 138412032);        //   4,194,304
    float* hps = (float*)(od + 142606336);        //   4,194,304
    float* hpq = (float*)(od + 146800640);        //   4,194,304

    char* ws = (char*)d_ws;
    const size_t NEED = 138444800;
    if (ws_size < NEED) return;
    u16*   ht  = (u16*)(ws);                      // 134,217,728
    u16*   w1e = (u16*)(ws + 134217728);          //   2,097,152
    u16*   w2e = (u16*)(ws + 136314880);          //   2,097,152
    float* b1e = (float*)(ws + 138412032);        //      16,384
    float* b2e = (float*)(ws + 138428416);        //      16,384

    transpose_stats_kernel<<<dim3(HW/64, NC/64, 16), 256, 0, stream>>>(x, xt, xps, xpq);
    fold_kernel<<<dim3(4, 16), 512, 0, stream>>>(w1, b1, xps, xpq, w1e, b1e);
    gemm1_kernel<<<dim3(1024), 512, 0, stream>>>(xt, w1e, b1e, ht, hps, hpq);
    fold_kernel<<<dim3(4, 16), 512, 0, stream>>>(w2, b2, hps, hpq, w2e, b2e);
    gemm2_kernel<<<dim3(1024), 256, 0, stream>>>(ht, w2e, b2e, out);
}

// Round 18
// 286.149 us; speedup vs baseline: 1.0796x; 1.0796x over previous
//
#include <hip/hip_runtime.h>
#include <hip/hip_bf16.h>
#include <cstdint>
#include <cstddef>

#define DEVI __device__ __forceinline__

typedef unsigned short u16;
using frag_ab = __attribute__((ext_vector_type(8))) short;   // 8 bf16 (4 VGPRs)
using f32x4   = __attribute__((ext_vector_type(4))) float;   // mfma acc / 16B NT store

constexpr int HW = 16384;   // 128*128 spatial
constexpr int NC = 256;     // channels (Cin = Cout = 256)

DEVI u16 bf16bits(float f) {
    union { float f; uint32_t u; } cv; cv.f = f;
    uint32_t u = cv.u;
    u += 0x7fffu + ((u >> 16) & 1u);   // RNE
    return (u16)(u >> 16);
}

DEVI void gload16(const void* g, void* l) {
    __builtin_amdgcn_global_load_lds(
        (const __attribute__((address_space(1))) uint32_t*)g,
        (__attribute__((address_space(3))) uint32_t*)l, 16, 0, 0);
}

// LDS slab: [row][64B]; 16B slot s at phys slot s ^ (row&3) ^ ((row>>2)&3).
DEVI frag_ab read_frag(const u16* slab, int row, int l4) {
    const int phys = (l4 ^ row ^ (row >> 2)) & 3;
    return *(const frag_ab*)((const char*)slab + row * 64 + phys * 16);
}

// ---------------- pass 1: x partial stats + transpose to xt[b][p][c] bf16 ----------------
__global__ __launch_bounds__(256) void transpose_stats_kernel(
    const float* __restrict__ x, u16* __restrict__ xt,
    float* __restrict__ ps, float* __restrict__ pq)
{
    constexpr int PADW = 68;                       // row pitch in u16 (136B)
    __shared__ __align__(16) u16 tile[64 * PADW];  // [px][ch]
    const int b = blockIdx.z, c0 = blockIdx.y * 64, p0 = blockIdx.x * 64;
    const int pblk = blockIdx.x;                   // 0..255
    const int t = threadIdx.x;
    const int lane = t & 63, w = t >> 6;
    const int pq_ = lane & 15, cq = lane >> 4;
    const int quad = w * 4 + cq;                   // ch-quad 0..15
    const float* xb = x + ((size_t)b * NC + c0) * HW + p0;

    float va[4][4];                                // [j=ch][i=px]
    float aS[4], aQ[4];
    #pragma unroll
    for (int j = 0; j < 4; ++j) {
        const float4 v = *(const float4*)(xb + (size_t)(quad * 4 + j) * HW + pq_ * 4);
        va[j][0] = v.x; va[j][1] = v.y; va[j][2] = v.z; va[j][3] = v.w;
        float s1 = v.x + v.y + v.z + v.w;
        float s2 = v.x*v.x + v.y*v.y + v.z*v.z + v.w*v.w;
        #pragma unroll
        for (int d = 1; d < 16; d <<= 1) {
            s1 += __shfl_xor(s1, d, 64);
            s2 += __shfl_xor(s2, d, 64);
        }
        aS[j] = s1; aQ[j] = s2;
    }
    if (pq_ == 0) {
        const float4 vs = {aS[0], aS[1], aS[2], aS[3]};
        const float4 vq = {aQ[0], aQ[1], aQ[2], aQ[3]};
        *(float4*)&ps[((size_t)b * 256 + pblk) * NC + c0 + quad * 4] = vs;
        *(float4*)&pq[((size_t)b * 256 + pblk) * NC + c0 + quad * 4] = vq;
    }
    #pragma unroll
    for (int i = 0; i < 4; ++i) {
        alignas(8) u16 pk[4];
        #pragma unroll
        for (int j = 0; j < 4; ++j) pk[j] = bf16bits(va[j][i]);
        *(uint2*)&tile[(pq_ * 4 + i) * PADW + quad * 4] = *(const uint2*)pk;
    }
    __syncthreads();
    const int pl = t >> 2, q = t & 3;
    u16* dst = xt + ((size_t)b * HW + p0 + pl) * NC + c0;
    #pragma unroll
    for (int s = 0; s < 2; ++s) {
        const int ch8 = q + s * 4;
        const uint2 lo = *(const uint2*)&tile[pl * PADW + ch8 * 8];
        const uint2 hi = *(const uint2*)&tile[pl * PADW + ch8 * 8 + 4];
        const uint4 o4 = {lo.x, lo.y, hi.x, hi.y};
        *(uint4*)(dst + ch8 * 8) = o4;
    }
}

// ---------------- fold (512 threads): reduce partials -> mu/rs, fold IN into weights/bias ----------------
__global__ __launch_bounds__(512) void fold_kernel(
    const float* __restrict__ w, const float* __restrict__ bias,
    const float* __restrict__ ps, const float* __restrict__ pq,
    u16* __restrict__ we, float* __restrict__ be)
{
    const int b = blockIdx.y, oc = blockIdx.x * 64;
    __shared__ float mu[NC], rs[NC];
    __shared__ float m1[2][NC], m2[2][NC];
    __shared__ __align__(16) float wt[64 * NC];
    const int t = threadIdx.x;
    {
        const int c = t & 255, half = t >> 8;      // half 0: i 0..127, half 1: i 128..255
        float s1 = 0.f, s2 = 0.f;
        const float* pp = ps + (size_t)b * 256 * NC + (size_t)half * 128 * NC + c;
        const float* qq = pq + (size_t)b * 256 * NC + (size_t)half * 128 * NC + c;
        for (int i = 0; i < 128; ++i) {
            s1 += pp[(size_t)i * NC];
            s2 += qq[(size_t)i * NC];
        }
        m1[half][c] = s1; m2[half][c] = s2;
    }
    // stage weights while stats settle: 64 rows x 1KB, 512 threads -> 8 float4 each
    #pragma unroll
    for (int i = 0; i < 8; ++i)
        *(float4*)&wt[i*2048 + t*4] = *(const float4*)&w[(size_t)oc*NC + i*2048 + t*4];
    __syncthreads();
    if (t < NC) {
        const float s1 = m1[0][t] + m1[1][t];
        const float s2 = m2[0][t] + m2[1][t];
        const float m = s1 * (1.0f / HW);
        mu[t] = m;
        rs[t] = rsqrtf(s2 * (1.0f / HW) - m * m + 1e-5f);
    }
    __syncthreads();
    const int o = oc + (t >> 3), q = t & 7;        // 8 threads per o-row, 32 ch each
    const float* wrow = &wt[(t >> 3) * NC];
    u16* werow = we + ((size_t)b * NC + o) * NC;
    float bacc = 0.f;
    for (int cc = 0; cc < 4; ++cc) {
        alignas(16) u16 pk[8];
        #pragma unroll
        for (int jj = 0; jj < 8; ++jj) {
            const int c = q*32 + cc*8 + jj;
            const float wv = wrow[c];
            bacc -= wv * mu[c] * rs[c];
            pk[jj] = bf16bits(wv * rs[c]);
        }
        *(uint4*)(werow + q*32 + cc*8) = *(const uint4*)pk;
    }
    bacc += __shfl_xor(bacc, 1, 64);
    bacc += __shfl_xor(bacc, 2, 64);
    bacc += __shfl_xor(bacc, 4, 64);
    if (q == 0) be[b*NC + o] = bias[o] + bacc;
}

// ---------------- fused GEMM: multi-tile pipeline, W in VGPRs, counted vmcnt (r16 shape) ----------------
// Grid 1024 x 4 waves; block = (b = blk>>6, stripgroup blk&63), 4 tiles pblk = g + 64*i.
// Counted waits, UNIFORMLY correct for all lanes: NS must count only all-lane vmem ops.
// stage1: 16 ht stores (all lanes) -> vmcnt(16) retires the 8 strip loads for every lane
// (l15==0 lanes additionally over-wait their 8 partial stores: harmless).
// stage2: 16 out stores (all lanes) -> vmcnt(16). vmcnt(0) only at tile 0.
template<int STAGE>
__global__ __launch_bounds__(256, 2) void gemm_kernel(
    const u16* __restrict__ pixM,   // [B*HW][NC] (xt or ht)
    const u16* __restrict__ wMat,   // [B][NC][NC] folded weights
    const float* __restrict__ biasE,// [B][NC]
    u16* __restrict__ outB,         // stage1: ht
    float* __restrict__ outF,       // stage2: out
    float* __restrict__ hps, float* __restrict__ hpq)
{
    __shared__ __align__(16) u16 ldsP[2][16384];  // 2 strips: 64 px x 256 k bf16 (32 KB each)

    const int b = blockIdx.x >> 6;
    const int g = blockIdx.x & 63;                // stripgroup: tiles pblk = g + 64*i
    const int tid = threadIdx.x;
    const int lane = tid & 63, wid = tid >> 6;    // 4 waves; wave owns outs [wid*64, +64)
    const int l15 = lane & 15, l4 = lane >> 4;

    const u16* gW = wMat + (size_t)b * NC * NC;

    const int rin  = lane >> 2;
    const int prow = wid * 16 + rin;
    const int psl  = ((lane & 3) ^ prow ^ (prow >> 2)) & 3;

    auto stageP = [&](int i, int buf) {
        const u16* gPt = pixM + ((size_t)b * HW + (g + 64 * i) * 64) * NC;
        #pragma unroll
        for (int ks = 0; ks < 8; ++ks)
            gload16(gPt + (size_t)prow * NC + ks * 32 + psl * 8,
                    (char*)ldsP[buf] + ks * 4096 + wid * 1024);
    };

    // ---- W quarter into VGPRs (one-time)
    frag_ab wf[8][4];
    {
        const u16* wb = gW + (size_t)(wid * 64 + l15) * NC + l4 * 8;
        #pragma unroll
        for (int ks = 0; ks < 8; ++ks)
            #pragma unroll
            for (int f = 0; f < 4; ++f)
                wf[ks][f] = *(const frag_ab*)(wb + (size_t)f * 16 * NC + ks * 32);
    }
    // ---- bias hoisted (loop vmem = stores only, for counted waits)
    float4 vb[4]; float bm[4];
    if constexpr (STAGE == 1) {
        #pragma unroll
        for (int mi = 0; mi < 4; ++mi)
            vb[mi] = *(const float4*)&biasE[b*NC + wid*64 + 16*mi + l4*4];
    } else {
        #pragma unroll
        for (int ni = 0; ni < 4; ++ni)
            bm[ni] = biasE[b*NC + wid*64 + 16*ni + l15];
    }

    stageP(0, 0);
    for (int i = 0; i < 4; ++i) {
        if (i == 0) {
            asm volatile("s_waitcnt vmcnt(0)" ::: "memory");
        } else {
            asm volatile("s_waitcnt vmcnt(16)" ::: "memory");   // uniform for all lanes
        }
        __builtin_amdgcn_s_barrier();              // strip i resident for all waves
        if (i < 3) stageP(i + 1, (i + 1) & 1);
        asm volatile("" ::: "memory");             // pin stage issue vs epilogue stores

        f32x4 acc[4][4];
        #pragma unroll
        for (int mi = 0; mi < 4; ++mi)
            #pragma unroll
            for (int ni = 0; ni < 4; ++ni)
                acc[mi][ni] = (f32x4){0.f, 0.f, 0.f, 0.f};

        const u16* bufb = ldsP[i & 1];
        #pragma unroll
        for (int ks = 0; ks < 8; ++ks) {
            const u16* pslab = bufb + ks * 2048;
            frag_ab pf[4];
            #pragma unroll
            for (int f = 0; f < 4; ++f)
                pf[f] = read_frag(pslab, 16 * f + l15, l4);
            #pragma unroll
            for (int ni = 0; ni < 4; ++ni)
                #pragma unroll
                for (int mi = 0; mi < 4; ++mi) {
                    if constexpr (STAGE == 1)   // A=W: reg dim = outs, lane dim = px
                        acc[mi][ni] = __builtin_amdgcn_mfma_f32_16x16x32_bf16(wf[ks][mi], pf[ni], acc[mi][ni], 0, 0, 0);
                    else                        // A=P: reg dim = px, lane dim = outs
                        acc[mi][ni] = __builtin_amdgcn_mfma_f32_16x16x32_bf16(pf[mi], wf[ks][ni], acc[mi][ni], 0, 0, 0);
                }
        }

        const int pblk = g + 64 * i;
        const int p0 = pblk * 64;
        if constexpr (STAGE == 1) {
            // acc: reg dim = out (wid*64+16mi+l4*4+r), lane dim = px (16ni+l15)
            u16* htbase = outB + ((size_t)b * HW + p0) * NC + wid * 64;
            #pragma unroll
            for (int mi = 0; mi < 4; ++mi) {
                const float bx[4] = {vb[mi].x, vb[mi].y, vb[mi].z, vb[mi].w};
                float s1r[4] = {0.f,0.f,0.f,0.f}, s2r[4] = {0.f,0.f,0.f,0.f};
                #pragma unroll
                for (int ni = 0; ni < 4; ++ni) {
                    u16* rowp = htbase + (size_t)(16*ni + l15) * NC;
                    alignas(8) u16 pk[4];
                    #pragma unroll
                    for (int r = 0; r < 4; ++r) {
                        const float v = fmaxf(acc[mi][ni][r] + bx[r], 0.f);
                        s1r[r] += v; s2r[r] += v * v;
                        pk[r] = bf16bits(v);
                    }
                    *(uint2*)&rowp[16*mi + l4*4] = *(const uint2*)pk;   // 8B store (all lanes)
                }
                #pragma unroll
                for (int r = 0; r < 4; ++r) {
                    float a1 = s1r[r], a2 = s2r[r];
                    #pragma unroll
                    for (int d = 1; d < 16; d <<= 1) {
                        a1 += __shfl_xor(a1, d, 64);
                        a2 += __shfl_xor(a2, d, 64);
                    }
                    s1r[r] = a1; s2r[r] = a2;
                }
                if (l15 == 0) {
                    const int o = wid*64 + 16*mi + l4*4;
                    const float4 w1v = {s1r[0], s1r[1], s1r[2], s1r[3]};
                    const float4 w2v = {s2r[0], s2r[1], s2r[2], s2r[3]};
                    *(float4*)&hps[((size_t)b * 256 + pblk) * NC + o] = w1v;
                    *(float4*)&hpq[((size_t)b * 256 + pblk) * NC + o] = w2v;
                }
            }
        } else {
            // acc: reg dim = px (16mi+l4*4+r), lane dim = out (wid*64+16ni+l15)
            // out is write-once, never re-read -> nontemporal 16B stores keep L2/L3 for ht/xt
            #pragma unroll
            for (int ni = 0; ni < 4; ++ni) {
                const int o = wid*64 + 16*ni + l15;
                float* colp = outF + ((size_t)b * NC + o) * HW + p0;
                #pragma unroll
                for (int mi = 0; mi < 4; ++mi) {
                    const f32x4 v = {fmaxf(acc[mi][ni][0] + bm[ni], 0.f),
                                     fmaxf(acc[mi][ni][1] + bm[ni], 0.f),
                                     fmaxf(acc[mi][ni][2] + bm[ni], 0.f),
                                     fmaxf(acc[mi][ni][3] + bm[ni], 0.f)};
                    __builtin_nontemporal_store(v, (f32x4*)&colp[16*mi + l4*4]);  // 16B NT store
                }
            }
        }
    }
}

extern "C" void kernel_launch(void* const* d_in, const int* in_sizes, int n_in,
                              void* d_out, int out_size, void* d_ws, size_t ws_size,
                              hipStream_t stream)
{
    (void)in_sizes; (void)n_in; (void)out_size;
    const float* x  = (const float*)d_in[0];
    const float* w1 = (const float*)d_in[1];
    const float* b1 = (const float*)d_in[2];
    const float* w2 = (const float*)d_in[3];
    const float* b2 = (const float*)d_in[4];
    float* out = (float*)d_out;

    // scratch carved out of d_out (268 MB): dead before gemm<2> overwrites it
    char* od = (char*)d_out;
    u16*   xt  = (u16*)od;                        // 134,217,728 B
    float* xps = (float*)(od + 134217728);        //   4,194,304
    float* xpq = (float*)(od + 138412032);        //   4,194,304
    float* hps = (float*)(od + 142606336);        //   4,194,304
    float* hpq = (float*)(od + 146800640);        //   4,194,304

    char* ws = (char*)d_ws;
    const size_t NEED = 138444800;
    if (ws_size < NEED) return;
    u16*   ht  = (u16*)(ws);                      // 134,217,728
    u16*   w1e = (u16*)(ws + 134217728);          //   2,097,152
    u16*   w2e = (u16*)(ws + 136314880);          //   2,097,152
    float* b1e = (float*)(ws + 138412032);        //      16,384
    float* b2e = (float*)(ws + 138428416);        //      16,384

    transpose_stats_kernel<<<dim3(HW/64, NC/64, 16), 256, 0, stream>>>(x, xt, xps, xpq);
    fold_kernel<<<dim3(4, 16), 512, 0, stream>>>(w1, b1, xps, xpq, w1e, b1e);
    gemm_kernel<1><<<dim3(1024), 256, 0, stream>>>(xt, w1e, b1e, ht, nullptr, hps, hpq);
    fold_kernel<<<dim3(4, 16), 512, 0, stream>>>(w2, b2, hps, hpq, w2e, b2e);
    gemm_kernel<2><<<dim3(1024), 256, 0, stream>>>(ht, w2e, b2e, nullptr, out, nullptr, nullptr);
}

// Round 19
// 282.621 us; speedup vs baseline: 1.0931x; 1.0125x over previous
//
#include <hip/hip_runtime.h>
#include <hip/hip_bf16.h>
#include <cstdint>
#include <cstddef>

#define DEVI __device__ __forceinline__

typedef unsigned short u16;
using frag_ab = __attribute__((ext_vector_type(8))) short;   // 8 bf16 (4 VGPRs)
using f32x4   = __attribute__((ext_vector_type(4))) float;   // mfma acc / 16B NT store

constexpr int HW = 16384;   // 128*128 spatial
constexpr int NC = 256;     // channels (Cin = Cout = 256)

DEVI u16 bf16bits(float f) {
    union { float f; uint32_t u; } cv; cv.f = f;
    uint32_t u = cv.u;
    u += 0x7fffu + ((u >> 16) & 1u);   // RNE
    return (u16)(u >> 16);
}

DEVI void gload16(const void* g, void* l) {
    __builtin_amdgcn_global_load_lds(
        (const __attribute__((address_space(1))) uint32_t*)g,
        (__attribute__((address_space(3))) uint32_t*)l, 16, 0, 0);
}

// LDS slab: [row][64B]; 16B slot s at phys slot s ^ (row&3) ^ ((row>>2)&3).
DEVI frag_ab read_frag(const u16* slab, int row, int l4) {
    const int phys = (l4 ^ row ^ (row >> 2)) & 3;
    return *(const frag_ab*)((const char*)slab + row * 64 + phys * 16);
}

// ---------------- pass 1: x partial stats + transpose to xt[b][p][c] bf16 ----------------
__global__ __launch_bounds__(256) void transpose_stats_kernel(
    const float* __restrict__ x, u16* __restrict__ xt,
    float* __restrict__ ps, float* __restrict__ pq)
{
    constexpr int PADW = 68;                       // row pitch in u16 (136B)
    __shared__ __align__(16) u16 tile[64 * PADW];  // [px][ch]
    const int b = blockIdx.z, c0 = blockIdx.y * 64, p0 = blockIdx.x * 64;
    const int pblk = blockIdx.x;                   // 0..255
    const int t = threadIdx.x;
    const int lane = t & 63, w = t >> 6;
    const int pq_ = lane & 15, cq = lane >> 4;
    const int quad = w * 4 + cq;                   // ch-quad 0..15
    const float* xb = x + ((size_t)b * NC + c0) * HW + p0;

    float va[4][4];                                // [j=ch][i=px]
    float aS[4], aQ[4];
    #pragma unroll
    for (int j = 0; j < 4; ++j) {
        const float4 v = *(const float4*)(xb + (size_t)(quad * 4 + j) * HW + pq_ * 4);
        va[j][0] = v.x; va[j][1] = v.y; va[j][2] = v.z; va[j][3] = v.w;
        float s1 = v.x + v.y + v.z + v.w;
        float s2 = v.x*v.x + v.y*v.y + v.z*v.z + v.w*v.w;
        #pragma unroll
        for (int d = 1; d < 16; d <<= 1) {
            s1 += __shfl_xor(s1, d, 64);
            s2 += __shfl_xor(s2, d, 64);
        }
        aS[j] = s1; aQ[j] = s2;
    }
    if (pq_ == 0) {
        const float4 vs = {aS[0], aS[1], aS[2], aS[3]};
        const float4 vq = {aQ[0], aQ[1], aQ[2], aQ[3]};
        *(float4*)&ps[((size_t)b * 256 + pblk) * NC + c0 + quad * 4] = vs;
        *(float4*)&pq[((size_t)b * 256 + pblk) * NC + c0 + quad * 4] = vq;
    }
    #pragma unroll
    for (int i = 0; i < 4; ++i) {
        alignas(8) u16 pk[4];
        #pragma unroll
        for (int j = 0; j < 4; ++j) pk[j] = bf16bits(va[j][i]);
        *(uint2*)&tile[(pq_ * 4 + i) * PADW + quad * 4] = *(const uint2*)pk;
    }
    __syncthreads();
    const int pl = t >> 2, q = t & 3;
    u16* dst = xt + ((size_t)b * HW + p0 + pl) * NC + c0;
    #pragma unroll
    for (int s = 0; s < 2; ++s) {
        const int ch8 = q + s * 4;
        const uint2 lo = *(const uint2*)&tile[pl * PADW + ch8 * 8];
        const uint2 hi = *(const uint2*)&tile[pl * PADW + ch8 * 8 + 4];
        const uint4 o4 = {lo.x, lo.y, hi.x, hi.y};
        *(uint4*)(dst + ch8 * 8) = o4;
    }
}

// ---------------- fold (512 threads): reduce partials -> mu/rs, fold IN into weights/bias ----------------
__global__ __launch_bounds__(512) void fold_kernel(
    const float* __restrict__ w, const float* __restrict__ bias,
    const float* __restrict__ ps, const float* __restrict__ pq,
    u16* __restrict__ we, float* __restrict__ be)
{
    const int b = blockIdx.y, oc = blockIdx.x * 64;
    __shared__ float mu[NC], rs[NC];
    __shared__ float m1[2][NC], m2[2][NC];
    __shared__ __align__(16) float wt[64 * NC];
    const int t = threadIdx.x;
    {
        const int c = t & 255, half = t >> 8;      // half 0: i 0..127, half 1: i 128..255
        float s1 = 0.f, s2 = 0.f;
        const float* pp = ps + (size_t)b * 256 * NC + (size_t)half * 128 * NC + c;
        const float* qq = pq + (size_t)b * 256 * NC + (size_t)half * 128 * NC + c;
        for (int i = 0; i < 128; ++i) {
            s1 += pp[(size_t)i * NC];
            s2 += qq[(size_t)i * NC];
        }
        m1[half][c] = s1; m2[half][c] = s2;
    }
    // stage weights while stats settle: 64 rows x 1KB, 512 threads -> 8 float4 each
    #pragma unroll
    for (int i = 0; i < 8; ++i)
        *(float4*)&wt[i*2048 + t*4] = *(const float4*)&w[(size_t)oc*NC + i*2048 + t*4];
    __syncthreads();
    if (t < NC) {
        const float s1 = m1[0][t] + m1[1][t];
        const float s2 = m2[0][t] + m2[1][t];
        const float m = s1 * (1.0f / HW);
        mu[t] = m;
        rs[t] = rsqrtf(s2 * (1.0f / HW) - m * m + 1e-5f);
    }
    __syncthreads();
    const int o = oc + (t >> 3), q = t & 7;        // 8 threads per o-row, 32 ch each
    const float* wrow = &wt[(t >> 3) * NC];
    u16* werow = we + ((size_t)b * NC + o) * NC;
    float bacc = 0.f;
    for (int cc = 0; cc < 4; ++cc) {
        alignas(16) u16 pk[8];
        #pragma unroll
        for (int jj = 0; jj < 8; ++jj) {
            const int c = q*32 + cc*8 + jj;
            const float wv = wrow[c];
            bacc -= wv * mu[c] * rs[c];
            pk[jj] = bf16bits(wv * rs[c]);
        }
        *(uint4*)(werow + q*32 + cc*8) = *(const uint4*)pk;
    }
    bacc += __shfl_xor(bacc, 1, 64);
    bacc += __shfl_xor(bacc, 2, 64);
    bacc += __shfl_xor(bacc, 4, 64);
    if (q == 0) be[b*NC + o] = bias[o] + bacc;
}

// ---------------- fused GEMM: r16 shape + SPLIT-STRIP arrival (half-strip waits) ----------------
// Grid 1024 x 4 waves; block = (b, stripgroup g), 4 tiles pblk = g + 64*i.
// Strip = 8 k-slices issued in order; per-wave vmcnt certifies halves:
//   tile top:  wait first half  -> vmcnt(4 + stores_prev)    [i==0: 4, else 20]
//   mid-tile:  wait second half -> vmcnt(stores_prev + next_strip) [24, last tile 16, i==0: 8]
// Slices are written by ALL 4 waves, so each wait is followed by s_barrier (a lane's
// vmcnt only certifies its own wave's loads). All counts use all-lane vmem ops only
// (16 ht/out stores); l15-lane partial stores merely over-wait (safe).
template<int STAGE>
__global__ __launch_bounds__(256, 2) void gemm_kernel(
    const u16* __restrict__ pixM,   // [B*HW][NC] (xt or ht)
    const u16* __restrict__ wMat,   // [B][NC][NC] folded weights
    const float* __restrict__ biasE,// [B][NC]
    u16* __restrict__ outB,         // stage1: ht
    float* __restrict__ outF,       // stage2: out
    float* __restrict__ hps, float* __restrict__ hpq)
{
    __shared__ __align__(16) u16 ldsP[2][16384];  // 2 strips: 64 px x 256 k bf16 (32 KB each)

    const int b = blockIdx.x >> 6;
    const int g = blockIdx.x & 63;                // stripgroup: tiles pblk = g + 64*i
    const int tid = threadIdx.x;
    const int lane = tid & 63, wid = tid >> 6;    // 4 waves; wave owns outs [wid*64, +64)
    const int l15 = lane & 15, l4 = lane >> 4;

    const u16* gW = wMat + (size_t)b * NC * NC;

    const int rin  = lane >> 2;
    const int prow = wid * 16 + rin;
    const int psl  = ((lane & 3) ^ prow ^ (prow >> 2)) & 3;

    auto stageP = [&](int i, int buf) {           // issues slices in ks order 0..7
        const u16* gPt = pixM + ((size_t)b * HW + (g + 64 * i) * 64) * NC;
        #pragma unroll
        for (int ks = 0; ks < 8; ++ks)
            gload16(gPt + (size_t)prow * NC + ks * 32 + psl * 8,
                    (char*)ldsP[buf] + ks * 4096 + wid * 1024);
    };

    // ---- W quarter into VGPRs (one-time)
    frag_ab wf[8][4];
    {
        const u16* wb = gW + (size_t)(wid * 64 + l15) * NC + l4 * 8;
        #pragma unroll
        for (int ks = 0; ks < 8; ++ks)
            #pragma unroll
            for (int f = 0; f < 4; ++f)
                wf[ks][f] = *(const frag_ab*)(wb + (size_t)f * 16 * NC + ks * 32);
    }
    // ---- bias hoisted (loop vmem = stores only, for counted waits)
    float4 vb[4]; float bm[4];
    if constexpr (STAGE == 1) {
        #pragma unroll
        for (int mi = 0; mi < 4; ++mi)
            vb[mi] = *(const float4*)&biasE[b*NC + wid*64 + 16*mi + l4*4];
    } else {
        #pragma unroll
        for (int ni = 0; ni < 4; ++ni)
            bm[ni] = biasE[b*NC + wid*64 + 16*ni + l15];
    }

    stageP(0, 0);
    for (int i = 0; i < 4; ++i) {
        // ---- wait FIRST HALF of strip i (slices 0..3), then converge
        if (i == 0) asm volatile("s_waitcnt vmcnt(4)"  ::: "memory");
        else        asm volatile("s_waitcnt vmcnt(20)" ::: "memory");
        __builtin_amdgcn_s_barrier();
        if (i < 3) stageP(i + 1, (i + 1) & 1);
        asm volatile("" ::: "memory");             // pin stage issue vs epilogue stores

        f32x4 acc[4][4];
        #pragma unroll
        for (int mi = 0; mi < 4; ++mi)
            #pragma unroll
            for (int ni = 0; ni < 4; ++ni)
                acc[mi][ni] = (f32x4){0.f, 0.f, 0.f, 0.f};

        const u16* bufb = ldsP[i & 1];
        #pragma unroll
        for (int ks = 0; ks < 4; ++ks) {           // first half: k = 0..127
            const u16* pslab = bufb + ks * 2048;
            frag_ab pf[4];
            #pragma unroll
            for (int f = 0; f < 4; ++f)
                pf[f] = read_frag(pslab, 16 * f + l15, l4);
            #pragma unroll
            for (int ni = 0; ni < 4; ++ni)
                #pragma unroll
                for (int mi = 0; mi < 4; ++mi) {
                    if constexpr (STAGE == 1)
                        acc[mi][ni] = __builtin_amdgcn_mfma_f32_16x16x32_bf16(wf[ks][mi], pf[ni], acc[mi][ni], 0, 0, 0);
                    else
                        acc[mi][ni] = __builtin_amdgcn_mfma_f32_16x16x32_bf16(pf[mi], wf[ks][ni], acc[mi][ni], 0, 0, 0);
                }
        }

        // ---- wait SECOND HALF of strip i (slices 4..7), converge (cross-wave chunks)
        if (i == 0)      asm volatile("s_waitcnt vmcnt(8)"  ::: "memory");
        else if (i < 3)  asm volatile("s_waitcnt vmcnt(24)" ::: "memory");
        else             asm volatile("s_waitcnt vmcnt(16)" ::: "memory");
        __builtin_amdgcn_s_barrier();

        #pragma unroll
        for (int ks = 4; ks < 8; ++ks) {           // second half: k = 128..255
            const u16* pslab = bufb + ks * 2048;
            frag_ab pf[4];
            #pragma unroll
            for (int f = 0; f < 4; ++f)
                pf[f] = read_frag(pslab, 16 * f + l15, l4);
            #pragma unroll
            for (int ni = 0; ni < 4; ++ni)
                #pragma unroll
                for (int mi = 0; mi < 4; ++mi) {
                    if constexpr (STAGE == 1)
                        acc[mi][ni] = __builtin_amdgcn_mfma_f32_16x16x32_bf16(wf[ks][mi], pf[ni], acc[mi][ni], 0, 0, 0);
                    else
                        acc[mi][ni] = __builtin_amdgcn_mfma_f32_16x16x32_bf16(pf[mi], wf[ks][ni], acc[mi][ni], 0, 0, 0);
                }
        }

        const int pblk = g + 64 * i;
        const int p0 = pblk * 64;
        if constexpr (STAGE == 1) {
            // acc: reg dim = out (wid*64+16mi+l4*4+r), lane dim = px (16ni+l15)
            u16* htbase = outB + ((size_t)b * HW + p0) * NC + wid * 64;
            #pragma unroll
            for (int mi = 0; mi < 4; ++mi) {
                const float bx[4] = {vb[mi].x, vb[mi].y, vb[mi].z, vb[mi].w};
                float s1r[4] = {0.f,0.f,0.f,0.f}, s2r[4] = {0.f,0.f,0.f,0.f};
                #pragma unroll
                for (int ni = 0; ni < 4; ++ni) {
                    u16* rowp = htbase + (size_t)(16*ni + l15) * NC;
                    alignas(8) u16 pk[4];
                    #pragma unroll
                    for (int r = 0; r < 4; ++r) {
                        const float v = fmaxf(acc[mi][ni][r] + bx[r], 0.f);
                        s1r[r] += v; s2r[r] += v * v;
                        pk[r] = bf16bits(v);
                    }
                    *(uint2*)&rowp[16*mi + l4*4] = *(const uint2*)pk;   // 8B store (all lanes)
                }
                #pragma unroll
                for (int r = 0; r < 4; ++r) {
                    float a1 = s1r[r], a2 = s2r[r];
                    #pragma unroll
                    for (int d = 1; d < 16; d <<= 1) {
                        a1 += __shfl_xor(a1, d, 64);
                        a2 += __shfl_xor(a2, d, 64);
                    }
                    s1r[r] = a1; s2r[r] = a2;
                }
                if (l15 == 0) {
                    const int o = wid*64 + 16*mi + l4*4;
                    const float4 w1v = {s1r[0], s1r[1], s1r[2], s1r[3]};
                    const float4 w2v = {s2r[0], s2r[1], s2r[2], s2r[3]};
                    *(float4*)&hps[((size_t)b * 256 + pblk) * NC + o] = w1v;
                    *(float4*)&hpq[((size_t)b * 256 + pblk) * NC + o] = w2v;
                }
            }
        } else {
            // acc: reg dim = px (16mi+l4*4+r), lane dim = out (wid*64+16ni+l15)
            // out is write-once, never re-read -> nontemporal 16B stores keep L2/L3 for ht/xt
            #pragma unroll
            for (int ni = 0; ni < 4; ++ni) {
                const int o = wid*64 + 16*ni + l15;
                float* colp = outF + ((size_t)b * NC + o) * HW + p0;
                #pragma unroll
                for (int mi = 0; mi < 4; ++mi) {
                    const f32x4 v = {fmaxf(acc[mi][ni][0] + bm[ni], 0.f),
                                     fmaxf(acc[mi][ni][1] + bm[ni], 0.f),
                                     fmaxf(acc[mi][ni][2] + bm[ni], 0.f),
                                     fmaxf(acc[mi][ni][3] + bm[ni], 0.f)};
                    __builtin_nontemporal_store(v, (f32x4*)&colp[16*mi + l4*4]);  // 16B NT store
                }
            }
        }
    }
}

extern "C" void kernel_launch(void* const* d_in, const int* in_sizes, int n_in,
                              void* d_out, int out_size, void* d_ws, size_t ws_size,
                              hipStream_t stream)
{
    (void)in_sizes; (void)n_in; (void)out_size;
    const float* x  = (const float*)d_in[0];
    const float* w1 = (const float*)d_in[1];
    const float* b1 = (const float*)d_in[2];
    const float* w2 = (const float*)d_in[3];
    const float* b2 = (const float*)d_in[4];
    float* out = (float*)d_out;

    // scratch carved out of d_out (268 MB): dead before gemm<2> overwrites it
    char* od = (char*)d_out;
    u16*   xt  = (u16*)od;                        // 134,217,728 B
    float* xps = (float*)(od + 134217728);        //   4,194,304
    float* xpq = (float*)(od + 138412032);        //   4,194,304
    float* hps = (float*)(od + 142606336);        //   4,194,304
    float* hpq = (float*)(od + 146800640);        //   4,194,304

    char* ws = (char*)d_ws;
    const size_t NEED = 138444800;
    if (ws_size < NEED) return;
    u16*   ht  = (u16*)(ws);                      // 134,217,728
    u16*   w1e = (u16*)(ws + 134217728);          //   2,097,152
    u16*   w2e = (u16*)(ws + 136314880);          //   2,097,152
    float* b1e = (float*)(ws + 138412032);        //      16,384
    float* b2e = (float*)(ws + 138428416);        //      16,384

    transpose_stats_kernel<<<dim3(HW/64, NC/64, 16), 256, 0, stream>>>(x, xt, xps, xpq);
    fold_kernel<<<dim3(4, 16), 512, 0, stream>>>(w1, b1, xps, xpq, w1e, b1e);
    gemm_kernel<1><<<dim3(1024), 256, 0, stream>>>(xt, w1e, b1e, ht, nullptr, hps, hpq);
    fold_kernel<<<dim3(4, 16), 512, 0, stream>>>(w2, b2, hps, hpq, w2e, b2e);
    gemm_kernel<2><<<dim3(1024), 256, 0, stream>>>(ht, w2e, b2e, nullptr, out, nullptr, nullptr);
}